// Round 5
// baseline (1322.560 us; speedup 1.0000x reference)
//
#include <hip/hip_runtime.h>
#include <stdint.h>
#include <math.h>

typedef unsigned short u16;
typedef __attribute__((ext_vector_type(8))) __bf16 bf16x8;
typedef __attribute__((ext_vector_type(4))) float f32x4;
typedef __attribute__((ext_vector_type(4))) unsigned short u16x4;

__device__ __forceinline__ float b2f(u16 u) {
    unsigned int i = ((unsigned int)u) << 16;
    float f; __builtin_memcpy(&f, &i, 4); return f;
}
__device__ __forceinline__ u16 f2b(float f) {
    unsigned int i; __builtin_memcpy(&i, &f, 4);
    i = (i + 0x7FFFu + ((i >> 16) & 1u)) >> 16;   // RNE
    return (u16)i;
}
// load 8 consecutive fp32, convert to bf16x8 (RNE)
__device__ __forceinline__ bf16x8 ld8_cvt(const float* p) {
    float4 f0 = *(const float4*)p, f1 = *(const float4*)(p + 4);
    u16 t[8] = {f2b(f0.x), f2b(f0.y), f2b(f0.z), f2b(f0.w),
                f2b(f1.x), f2b(f1.y), f2b(f1.z), f2b(f1.w)};
    bf16x8 r; __builtin_memcpy(&r, t, 16); return r;
}

// async global->LDS 16B copy (global_load_lds_dwordx4). LDS dest must be
// wave-uniform base + lane*16 — all call sites below satisfy this.
__device__ __forceinline__ void glds16(const u16* g, u16* l) {
    __builtin_amdgcn_global_load_lds(
        (const __attribute__((address_space(1))) void*)g,
        (__attribute__((address_space(3))) void*)l, 16, 0, 0);
}

// ---------------------------------------------------------------------------
// Transpose + fp32->bf16 convert: in[R][C] fp32 -> out[C][R] bf16.
// block (32,8), grid (C/32, R/32)
// ---------------------------------------------------------------------------
__global__ __launch_bounds__(256) void transpose_f32_bf16(
    const float* __restrict__ in, u16* __restrict__ out, int R, int C)
{
    __shared__ float t[32][33];
    int bx = blockIdx.x * 32, by = blockIdx.y * 32;
    int x = threadIdx.x, y = threadIdx.y;
    #pragma unroll
    for (int j = 0; j < 32; j += 8)
        t[y + j][x] = in[(size_t)(by + y + j) * C + bx + x];
    __syncthreads();
    #pragma unroll
    for (int j = 0; j < 32; j += 8)
        out[(size_t)(bx + y + j) * R + by + x] = f2b(t[x][y + j]);
}

// ---------------------------------------------------------------------------
// Elementwise fp32 -> bf16 convert (for x before the QKV GEMM).
// ---------------------------------------------------------------------------
__global__ __launch_bounds__(256) void cvt_f32_bf16(
    const float* __restrict__ in, u16* __restrict__ out)
{
    size_t i = ((size_t)blockIdx.x * 256 + threadIdx.x) * 8;
    *(bf16x8*)(out + i) = ld8_cvt(in + i);
}

// ---------------------------------------------------------------------------
// 256x256-tile GEMM (8 waves / 512 threads), BK=32, counted-vmcnt dbuf.
// C[M,N] = A[M,K] @ Bt[N,K]^T (+bias/epilogue). A,Bt bf16; acc fp32.
// Per K-step a block runs 256 MFMAs (~1240 CU-cycles of matrix work) — the
// structural fix for the 128^2 kernel's exposed-latency ceiling (R4: 16%
// MfmaUtil, 81us): prefetch issued one step ahead now has a full compute
// phase to land, and barrier cost is amortized 16x better per MFMA.
// LDS 64 KB (2 buf x 2 mat x 256x32 bf16); 1 block/CU; VGPR~200 (cap 256).
// Wave grid 2x4: wave wm=wave>>2 owns rows wm*128..+127, wn=wave&3 owns
// cols wn*64..+63; per-wave acc = 8x4 f32x4 fragments.
// Bank note: 64B rows => wave-read load is evenly spread (8 words/bank),
// no swizzle needed (and glds forbids dest swizzle anyway).
// EPI 1: gelu_erf(acc+bias) -> bf16 C.  EPI 2: QKV permuted store.
// ---------------------------------------------------------------------------
template<int EPI>
__global__ __launch_bounds__(512, 2) void gemm256(
    const u16* __restrict__ A, const u16* __restrict__ Bt, int N, int K,
    u16* __restrict__ C, const float* __restrict__ bias,
    u16* __restrict__ qo, u16* __restrict__ ko, u16* __restrict__ vo,
    const float* __restrict__ bq, const float* __restrict__ bk,
    const float* __restrict__ bv)
{
    __shared__ __align__(16) u16 Asm[2][256 * 32];
    __shared__ __align__(16) u16 Bsm[2][256 * 32];
    const int tid  = threadIdx.x;
    const int lane = tid & 63, wave = tid >> 6;
    const int lrow = lane & 15, quad = lane >> 4;
    const int wm = wave >> 2, wn = wave & 3;
    const int bm = blockIdx.x * 256, bn = blockIdx.y * 256;

    // staging: thread covers rows (tid>>2) and (tid>>2)+128,
    // col elems (tid&3)*8..+7; LDS dest = tid*16B (+8KB for second half).
    const int srow = tid >> 2, skol = (tid & 3) * 8;
    const u16* gA = A  + (size_t)(bm + srow) * K + skol;
    const u16* gB = Bt + (size_t)(bn + srow) * K + skol;
    const size_t rstep = (size_t)128 * K;

    f32x4 acc[8][4] = {};

#define STAGE256(T, BUF) do {                                              \
        glds16(gA + (size_t)(T) * 32,         &Asm[BUF][(size_t)tid * 8]); \
        glds16(gA + (size_t)(T) * 32 + rstep, &Asm[BUF][((size_t)tid + 512) * 8]); \
        glds16(gB + (size_t)(T) * 32,         &Bsm[BUF][(size_t)tid * 8]); \
        glds16(gB + (size_t)(T) * 32 + rstep, &Bsm[BUF][((size_t)tid + 512) * 8]); \
    } while (0)

    const int ntile = K >> 5;
    // prologue: T0 -> buf0, T1 -> buf1; wait T0 (4 newest stay in flight)
    STAGE256(0, 0);
    STAGE256(1, 1);
    asm volatile("s_waitcnt vmcnt(4)" ::: "memory");
    __builtin_amdgcn_s_barrier();
    __builtin_amdgcn_sched_barrier(0);

    for (int t = 0; t < ntile; ++t) {
        const int cur = t & 1;
        bf16x8 af[8], bfr[4];
        #pragma unroll
        for (int mt = 0; mt < 8; mt++)
            af[mt] = *(const bf16x8*)&Asm[cur][(wm * 128 + mt * 16 + lrow) * 32 + quad * 8];
        #pragma unroll
        for (int nt = 0; nt < 4; nt++)
            bfr[nt] = *(const bf16x8*)&Bsm[cur][(wn * 64 + nt * 16 + lrow) * 32 + quad * 8];
        #pragma unroll
        for (int mt = 0; mt < 8; mt++)
            #pragma unroll
            for (int nt = 0; nt < 4; nt++)
                acc[mt][nt] = __builtin_amdgcn_mfma_f32_16x16x32_bf16(
                    af[mt], bfr[nt], acc[mt][nt], 0, 0, 0);

        if (t + 1 < ntile) {
            __builtin_amdgcn_sched_barrier(0);
            __builtin_amdgcn_s_barrier();        // all waves done reading buf[cur]
            if (t + 2 < ntile) {
                STAGE256(t + 2, cur);            // refill the just-freed buffer
                asm volatile("s_waitcnt vmcnt(4)" ::: "memory");  // T+1 landed
            } else {
                asm volatile("s_waitcnt vmcnt(0)" ::: "memory");  // drain last
            }
            __builtin_amdgcn_s_barrier();        // tile t+1 resident everywhere
            __builtin_amdgcn_sched_barrier(0);
        }
    }
#undef STAGE256

    // epilogue: C/D layout col = lane&15, row = quad*4 + reg
    #pragma unroll
    for (int nt = 0; nt < 4; nt++) {
        int col = bn + wn * 64 + nt * 16 + lrow;
        int mat = 0, hh = 0, dd = 0;
        float bval;
        if (EPI == 2) {
            mat  = col >> 10; int dcol = col & 1023;
            hh = dcol >> 6;   dd = dcol & 63;
            const float* bp = (mat == 0) ? bq : ((mat == 1) ? bk : bv);
            bval = bp[dcol];
        } else {
            bval = bias[col];
        }
        #pragma unroll
        for (int mt = 0; mt < 8; mt++) {
            #pragma unroll
            for (int r = 0; r < 4; r++) {
                int row = bm + wm * 128 + mt * 16 + quad * 4 + r;
                float v = acc[mt][nt][r] + bval;
                if (EPI == 1) v = 0.5f * v * (1.0f + erff(v * 0.70710678118654752f));
                if (EPI == 2) {
                    int b = row >> 9, s = row & 511;   // b = batch within group
                    u16* dst = (mat == 0) ? qo : ((mat == 1) ? ko : vo);
                    dst[(((size_t)(b * 16 + hh)) * 512 + s) * 64 + dd] = f2b(v);
                } else {
                    C[(size_t)row * N + col] = f2b(v);
                }
            }
        }
    }
}

// ---------------------------------------------------------------------------
// 128xBN GEMM (4 waves) — counted-vmcnt dbuf (R4-verified). Used for the
// N=1024 GEMMs (Wo, W2) where a 256^2 grid would idle 3/4 of the CUs.
// ---------------------------------------------------------------------------
template<int EPI, int BN>
__global__ __launch_bounds__(256) void gemm_bt(
    const u16* __restrict__ A, const u16* __restrict__ Bt, int N, int K,
    u16* __restrict__ C, const float* __restrict__ bias,
    u16* __restrict__ qo, u16* __restrict__ ko, u16* __restrict__ vo,
    const float* __restrict__ bq, const float* __restrict__ bk,
    const float* __restrict__ bv)
{
    __shared__ __align__(16) u16 Asm[2][128 * 32];
    __shared__ __align__(16) u16 Bsm[2][BN * 32];
    const int tid  = threadIdx.x;
    const int lane = tid & 63;
    const int wave = tid >> 6;
    const int lrow = lane & 15, quad = lane >> 4;
    const int bm = blockIdx.x * 128, bn = blockIdx.y * BN;

    const int srow = tid >> 2;
    const int skol = (tid & 3) * 8;
    const u16* gA0 = A  + (size_t)(bm + srow) * K + skol;
    const u16* gA1 = gA0 + (size_t)64 * K;
    const u16* gB0 = Bt + (size_t)(bn + srow) * K + skol;
    const u16* gB1 = gB0 + (size_t)64 * K;   // used only when BN==128

    const int wm = wave >> 1, wn = wave & 1;
    constexpr int NT = (BN == 128) ? 4 : 2;
    f32x4 acc[4][NT] = {};

    glds16(gA0, &Asm[0][(size_t)tid * 8]);
    glds16(gA1, &Asm[0][((size_t)tid + 256) * 8]);
    if constexpr (BN == 128) glds16(gB1, &Bsm[0][((size_t)tid + 256) * 8]);
    glds16(gB0, &Bsm[0][(size_t)tid * 8]);

    int cur = 0;
    for (int kt = 0; kt < K; kt += 32) {
        const int nxt = kt + 32;
        if (nxt < K) {
            glds16(gA0 + nxt, &Asm[cur ^ 1][(size_t)tid * 8]);
            glds16(gA1 + nxt, &Asm[cur ^ 1][((size_t)tid + 256) * 8]);
            if constexpr (BN == 128)
                glds16(gB1 + nxt, &Bsm[cur ^ 1][((size_t)tid + 256) * 8]);
            glds16(gB0 + nxt, &Bsm[cur ^ 1][(size_t)tid * 8]);
            if constexpr (BN == 128)
                asm volatile("s_waitcnt vmcnt(4)" ::: "memory");
            else
                asm volatile("s_waitcnt vmcnt(3)" ::: "memory");
        } else {
            asm volatile("s_waitcnt vmcnt(0)" ::: "memory");
        }
        __builtin_amdgcn_s_barrier();
        __builtin_amdgcn_sched_barrier(0);

        bf16x8 af[4], bfr[NT];
        #pragma unroll
        for (int mt = 0; mt < 4; mt++)
            af[mt] = *(const bf16x8*)&Asm[cur][(wm * 64 + mt * 16 + lrow) * 32 + quad * 8];
        #pragma unroll
        for (int nt = 0; nt < NT; nt++)
            bfr[nt] = *(const bf16x8*)&Bsm[cur][(wn * (BN / 2) + nt * 16 + lrow) * 32 + quad * 8];
        #pragma unroll
        for (int mt = 0; mt < 4; mt++)
            #pragma unroll
            for (int nt = 0; nt < NT; nt++)
                acc[mt][nt] = __builtin_amdgcn_mfma_f32_16x16x32_bf16(
                    af[mt], bfr[nt], acc[mt][nt], 0, 0, 0);

        __builtin_amdgcn_sched_barrier(0);
        __builtin_amdgcn_s_barrier();
        cur ^= 1;
    }

    #pragma unroll
    for (int nt = 0; nt < NT; nt++) {
        int col = bn + wn * (BN / 2) + nt * 16 + lrow;
        int mat = 0, hh = 0, dd = 0;
        float bval;
        if (EPI == 2) {
            mat  = col >> 10; int dcol = col & 1023;
            hh = dcol >> 6;   dd = dcol & 63;
            const float* bp = (mat == 0) ? bq : ((mat == 1) ? bk : bv);
            bval = bp[dcol];
        } else {
            bval = bias[col];
        }
        #pragma unroll
        for (int mt = 0; mt < 4; mt++) {
            #pragma unroll
            for (int r = 0; r < 4; r++) {
                int row = bm + wm * 64 + mt * 16 + quad * 4 + r;
                float v = acc[mt][nt][r] + bval;
                if (EPI == 1) v = 0.5f * v * (1.0f + erff(v * 0.70710678118654752f));
                if (EPI == 2) {
                    int b = row >> 9, s = row & 511;
                    u16* dst = (mat == 0) ? qo : ((mat == 1) ? ko : vo);
                    dst[(((size_t)(b * 16 + hh)) * 512 + s) * 64 + dd] = f2b(v);
                } else {
                    C[(size_t)row * N + col] = f2b(v);
                }
            }
        }
    }
}

// ---------------------------------------------------------------------------
// Flash attention (unchanged from R3/R4 — verified): 2-phase pipeline,
// K dbuf via glds, V reg-staged, adj prefetch, one barrier per KV-tile,
// batch-in-group -> XCD swizzle.
// ---------------------------------------------------------------------------
__global__ __launch_bounds__(256) void attn_kernel(
    const u16* __restrict__ Q, const u16* __restrict__ Kb, const u16* __restrict__ Vb,
    const float* __restrict__ adj, const int* __restrict__ mask, u16* __restrict__ ctx)
{
    const int S = 512, H = 16;
    __shared__ __align__(16) u16 Ksm[2][32 * 64];
    __shared__ __align__(16) u16 Vt [2][64 * 32];
    __shared__ __align__(16) u16 Psm[4][16 * 32];

    int tid = threadIdx.x, lane = tid & 63, wave = tid >> 6;
    int lrow = lane & 15, quad = lane >> 4;

    int orig = (blockIdx.z * 16 + blockIdx.y) * 8 + blockIdx.x;
    int b  = orig & 7;
    int h  = (orig >> 3) & 15;
    int qt = orig >> 7;

    size_t headoff = ((size_t)(b * H + h)) * S * 64;
    const u16* qp = Q + headoff;
    const u16* kp = Kb + headoff;
    const u16* vp = Vb + headoff;
    const float* adjb = adj + (size_t)b * S * S;
    const int* maskb = mask + b * S;
    int q0 = qt * 64 + wave * 16;

    bf16x8 qf0 = *(const bf16x8*)(qp + (size_t)(q0 + lrow) * 64 + quad * 8);
    bf16x8 qf1 = *(const bf16x8*)(qp + (size_t)(q0 + lrow) * 64 + 32 + quad * 8);

    float m_run[4] = {-1e30f, -1e30f, -1e30f, -1e30f};
    float l_run[4] = {0.f, 0.f, 0.f, 0.f};
    f32x4 o[4] = {};

    int str = tid >> 3;
    int stc = (tid & 7) * 8;

    glds16(kp + (size_t)str * 64 + stc, &Ksm[0][str * 64 + stc]);
    bf16x8 vcur = *(const bf16x8*)(vp + (size_t)str * 64 + stc);
    __syncthreads();

    int cur = 0;
    for (int kt = 0; kt < S; kt += 32) {
        const int nxt = kt + 32;
        bf16x8 vnxt;
        if (nxt < S) {
            glds16(kp + (size_t)(nxt + str) * 64 + stc, &Ksm[cur ^ 1][str * 64 + stc]);
            vnxt = *(const bf16x8*)(vp + (size_t)(nxt + str) * 64 + stc);
        }
        {
            const u16* tv = (const u16*)&vcur;
            #pragma unroll
            for (int j = 0; j < 8; j++) Vt[cur][(stc + j) * 32 + str] = tv[j];
        }
        float adjv[2][4];
        #pragma unroll
        for (int f = 0; f < 2; f++)
            #pragma unroll
            for (int r = 0; r < 4; r++)
                adjv[f][r] = adjb[(size_t)(q0 + quad * 4 + r) * S + kt + f * 16 + lrow];

        f32x4 sc[2];
        #pragma unroll
        for (int f = 0; f < 2; f++) {
            f32x4 cf = {};
            bf16x8 kf0 = *(const bf16x8*)&Ksm[cur][(f * 16 + lrow) * 64 + quad * 8];
            bf16x8 kf1 = *(const bf16x8*)&Ksm[cur][(f * 16 + lrow) * 64 + 32 + quad * 8];
            cf = __builtin_amdgcn_mfma_f32_16x16x32_bf16(qf0, kf0, cf, 0, 0, 0);
            cf = __builtin_amdgcn_mfma_f32_16x16x32_bf16(qf1, kf1, cf, 0, 0, 0);
            int key = kt + f * 16 + lrow;
            float mterm = maskb[key] ? -1e9f : 0.0f;
            #pragma unroll
            for (int r = 0; r < 4; r++)
                sc[f][r] = cf[r] * 0.125f + mterm + adjv[f][r];
        }

        float mx[4], al[4], sm[4];
        #pragma unroll
        for (int r = 0; r < 4; r++) mx[r] = fmaxf(sc[0][r], sc[1][r]);
        #pragma unroll
        for (int mk = 1; mk < 16; mk <<= 1)
            #pragma unroll
            for (int r = 0; r < 4; r++) mx[r] = fmaxf(mx[r], __shfl_xor(mx[r], mk));
        #pragma unroll
        for (int r = 0; r < 4; r++) {
            float mn = fmaxf(m_run[r], mx[r]);
            al[r] = __expf(fminf(m_run[r] - mn, 0.f));
            m_run[r] = mn;
        }
        #pragma unroll
        for (int f = 0; f < 2; f++)
            #pragma unroll
            for (int r = 0; r < 4; r++)
                sc[f][r] = __expf(fminf(sc[f][r] - m_run[r], 0.f));
        #pragma unroll
        for (int r = 0; r < 4; r++) sm[r] = sc[0][r] + sc[1][r];
        #pragma unroll
        for (int mk = 1; mk < 16; mk <<= 1)
            #pragma unroll
            for (int r = 0; r < 4; r++) sm[r] += __shfl_xor(sm[r], mk);
        #pragma unroll
        for (int r = 0; r < 4; r++) l_run[r] = l_run[r] * al[r] + sm[r];
        #pragma unroll
        for (int nt = 0; nt < 4; nt++)
            #pragma unroll
            for (int r = 0; r < 4; r++) o[nt][r] *= al[r];

        #pragma unroll
        for (int f = 0; f < 2; f++)
            #pragma unroll
            for (int r = 0; r < 4; r++)
                Psm[wave][(quad * 4 + r) * 32 + f * 16 + lrow] = f2b(sc[f][r]);
        bf16x8 pa = *(const bf16x8*)&Psm[wave][lrow * 32 + quad * 8];

        __syncthreads();
        #pragma unroll
        for (int nt = 0; nt < 4; nt++) {
            bf16x8 vf = *(const bf16x8*)&Vt[cur][(nt * 16 + lrow) * 32 + quad * 8];
            o[nt] = __builtin_amdgcn_mfma_f32_16x16x32_bf16(pa, vf, o[nt], 0, 0, 0);
        }
        if (nxt < S) vcur = vnxt;
        cur ^= 1;
    }

    #pragma unroll
    for (int nt = 0; nt < 4; nt++)
        #pragma unroll
        for (int r = 0; r < 4; r++) {
            int qrow = q0 + quad * 4 + r;
            ctx[((size_t)b * 512 + qrow) * 1024 + h * 64 + nt * 16 + lrow] =
                f2b(o[nt][r] / l_run[r]);
        }
}

// ---------------------------------------------------------------------------
// out = LayerNorm(X + Y): mean over D=1024, unbiased std (ddof=1), /(std+1e-6)
// MODE 0: X fp32, Y bf16, out bf16   MODE 1: X bf16, Y bf16, out fp32
// ---------------------------------------------------------------------------
template<int MODE>
__global__ __launch_bounds__(256) void add_ln(
    const void* __restrict__ Xv, const void* __restrict__ Yv,
    const float* __restrict__ gamma, const float* __restrict__ beta,
    void* __restrict__ outv)
{
    const int D = 1024;
    int row = blockIdx.x, tid = threadIdx.x;
    int lane = tid & 63, wave = tid >> 6;
    size_t base = (size_t)row * D + tid * 4;

    float x[4];
    if (MODE == 0) {
        float4 xf = *(const float4*)((const float*)Xv + base);
        u16x4  uy = *(const u16x4*)((const u16*)Yv + base);
        x[0] = xf.x + b2f(uy[0]); x[1] = xf.y + b2f(uy[1]);
        x[2] = xf.z + b2f(uy[2]); x[3] = xf.w + b2f(uy[3]);
    } else {
        u16x4 ux = *(const u16x4*)((const u16*)Xv + base);
        u16x4 uy = *(const u16x4*)((const u16*)Yv + base);
        #pragma unroll
        for (int j = 0; j < 4; j++) x[j] = b2f(ux[j]) + b2f(uy[j]);
    }

    float s = x[0] + x[1] + x[2] + x[3];
    #pragma unroll
    for (int mk = 1; mk < 64; mk <<= 1) s += __shfl_xor(s, mk);
    __shared__ float red[8];
    if (lane == 0) red[wave] = s;
    __syncthreads();
    float mean = (red[0] + red[1] + red[2] + red[3]) * (1.0f / 1024.0f);

    float c[4], q = 0.f;
    #pragma unroll
    for (int j = 0; j < 4; j++) { c[j] = x[j] - mean; q += c[j] * c[j]; }
    #pragma unroll
    for (int mk = 1; mk < 64; mk <<= 1) q += __shfl_xor(q, mk);
    if (lane == 0) red[4 + wave] = q;
    __syncthreads();
    float var = (red[4] + red[5] + red[6] + red[7]) * (1.0f / 1023.0f);
    float inv = 1.0f / (sqrtf(var) + 1e-6f);

    float4 g4 = *(const float4*)(gamma + tid * 4);
    float4 b4 = *(const float4*)(beta + tid * 4);
    float gv[4] = {g4.x, g4.y, g4.z, g4.w};
    float bv[4] = {b4.x, b4.y, b4.z, b4.w};
    if (MODE == 0) {
        u16x4 ov;
        #pragma unroll
        for (int j = 0; j < 4; j++) ov[j] = f2b(gv[j] * c[j] * inv + bv[j]);
        *(u16x4*)((u16*)outv + base) = ov;
    } else {
        float4 ov;
        ov.x = gv[0] * c[0] * inv + bv[0];
        ov.y = gv[1] * c[1] * inv + bv[1];
        ov.z = gv[2] * c[2] * inv + bv[2];
        ov.w = gv[3] * c[3] * inv + bv[3];
        *(float4*)((float*)outv + base) = ov;
    }
}

// ---------------------------------------------------------------------------
// Workspace (bf16 unless noted), 96 MB peak:
//   [ 0, 6) Wqkv_t  [ 6, 8) Wo_t  [ 8,16) W1_t  [16,24) W2_t
//   [24,56) out1 (16384x1024)
//   attn phase (per 8-batch group): [56,64) q [64,72) k [72,80) v
//     [80,88) ctx [88,96) x_bf16 (QKV A operand), then overwritten by attn_out
//   FFN phase (per 4096-row chunk): [56,88) hidden [88,96) ffn
// ---------------------------------------------------------------------------
extern "C" void kernel_launch(void* const* d_in, const int* in_sizes, int n_in,
                              void* d_out, int out_size, void* d_ws, size_t ws_size,
                              hipStream_t stream)
{
    const float* x    = (const float*)d_in[0];
    const int*   mask = (const int*)d_in[1];
    const float* adj  = (const float*)d_in[2];
    const float* Wq = (const float*)d_in[4];  const float* bq = (const float*)d_in[5];
    const float* Wk = (const float*)d_in[6];  const float* bk = (const float*)d_in[7];
    const float* Wv = (const float*)d_in[8];  const float* bv = (const float*)d_in[9];
    const float* Wo = (const float*)d_in[10]; const float* bo = (const float*)d_in[11];
    const float* W1 = (const float*)d_in[12]; const float* b1 = (const float*)d_in[13];
    const float* W2 = (const float*)d_in[14]; const float* b2 = (const float*)d_in[15];
    const float* gamma = (const float*)d_in[16];
    const float* beta  = (const float*)d_in[17];
    float* out = (float*)d_out;

    const size_t MB = 1024ull * 1024;
    char* w = (char*)d_ws;
    u16* Wqkv_t = (u16*)(w + 0 * MB);
    u16* Wo_t   = (u16*)(w + 6 * MB);
    u16* W1_t   = (u16*)(w + 8 * MB);
    u16* W2_t   = (u16*)(w + 16 * MB);
    u16* out1   = (u16*)(w + 24 * MB);
    u16* qg     = (u16*)(w + 56 * MB);
    u16* kg     = (u16*)(w + 64 * MB);
    u16* vg     = (u16*)(w + 72 * MB);
    u16* ctxg   = (u16*)(w + 80 * MB);
    u16* aog    = (u16*)(w + 88 * MB);   // x_bf16 during QKV, attn_out after Wo
    u16* hid    = (u16*)(w + 56 * MB);   // overlays q/k/v/ctx (dead in FFN phase)
    u16* ffn    = (u16*)(w + 88 * MB);   // overlays attn_out

    dim3 tb(32, 8);
    transpose_f32_bf16<<<dim3(32, 32),  tb, 0, stream>>>(Wq, Wqkv_t,                1024, 1024);
    transpose_f32_bf16<<<dim3(32, 32),  tb, 0, stream>>>(Wk, Wqkv_t + 1024ull*1024, 1024, 1024);
    transpose_f32_bf16<<<dim3(32, 32),  tb, 0, stream>>>(Wv, Wqkv_t + 2048ull*1024, 1024, 1024);
    transpose_f32_bf16<<<dim3(32, 32),  tb, 0, stream>>>(Wo, Wo_t,                  1024, 1024);
    transpose_f32_bf16<<<dim3(128, 32), tb, 0, stream>>>(W1, W1_t,                  1024, 4096);
    transpose_f32_bf16<<<dim3(32, 128), tb, 0, stream>>>(W2, W2_t,                  4096, 1024);

    // ---- attention phase: 4 groups of 8 batches (4096 rows each) ----
    for (int g = 0; g < 4; g++) {
        const float* xg = x + (size_t)g * 4096 * 1024;
        cvt_f32_bf16<<<2048, 256, 0, stream>>>(xg, aog);
        gemm256<2><<<dim3(16, 12), 512, 0, stream>>>(aog, Wqkv_t, 3072, 1024,
            nullptr, nullptr, qg, kg, vg, bq, bk, bv);
        attn_kernel<<<dim3(8, 16, 8), 256, 0, stream>>>(qg, kg, vg,
            adj + (size_t)g * 8 * 512 * 512, mask + g * 8 * 512, ctxg);
        gemm_bt<0, 64><<<dim3(32, 16), 256, 0, stream>>>(ctxg, Wo_t, 1024, 1024,
            aog, bo, nullptr, nullptr, nullptr, nullptr, nullptr, nullptr);
        add_ln<0><<<4096, 256, 0, stream>>>(xg, aog, gamma, beta,
            out1 + (size_t)g * 4096 * 1024);
    }

    // ---- FFN phase: 4 row chunks of 4096 ----
    for (int c = 0; c < 4; c++) {
        const u16* o1c = out1 + (size_t)c * 4096 * 1024;
        gemm256<1><<<dim3(16, 16), 512, 0, stream>>>(o1c, W1_t, 4096, 1024,
            hid, b1, nullptr, nullptr, nullptr, nullptr, nullptr, nullptr);
        gemm_bt<0, 64><<<dim3(32, 16), 256, 0, stream>>>(hid, W2_t, 1024, 4096,
            ffn, b2, nullptr, nullptr, nullptr, nullptr, nullptr, nullptr);
        add_ln<1><<<4096, 256, 0, stream>>>(o1c, ffn, gamma, beta,
            out + (size_t)c * 4096 * 1024);
    }
}

// Round 7
// 1271.784 us; speedup vs baseline: 1.0399x; 1.0399x over previous
//
#include <hip/hip_runtime.h>
#include <stdint.h>
#include <math.h>

typedef unsigned short u16;
typedef __attribute__((ext_vector_type(8))) __bf16 bf16x8;
typedef __attribute__((ext_vector_type(4))) float f32x4;
typedef __attribute__((ext_vector_type(4))) unsigned short u16x4;

__device__ __forceinline__ float b2f(u16 u) {
    unsigned int i = ((unsigned int)u) << 16;
    float f; __builtin_memcpy(&f, &i, 4); return f;
}
__device__ __forceinline__ u16 f2b(float f) {
    unsigned int i; __builtin_memcpy(&i, &f, 4);
    i = (i + 0x7FFFu + ((i >> 16) & 1u)) >> 16;   // RNE
    return (u16)i;
}
// load 8 consecutive fp32, convert to bf16x8 (RNE)
__device__ __forceinline__ bf16x8 ld8_cvt(const float* p) {
    float4 f0 = *(const float4*)p, f1 = *(const float4*)(p + 4);
    u16 t[8] = {f2b(f0.x), f2b(f0.y), f2b(f0.z), f2b(f0.w),
                f2b(f1.x), f2b(f1.y), f2b(f1.z), f2b(f1.w)};
    bf16x8 r; __builtin_memcpy(&r, t, 16); return r;
}

// async global->LDS 16B copy. LDS dest must be wave-uniform base + lane*16.
__device__ __forceinline__ void glds16(const u16* g, u16* l) {
    __builtin_amdgcn_global_load_lds(
        (const __attribute__((address_space(1))) void*)g,
        (__attribute__((address_space(3))) void*)l, 16, 0, 0);
}

// ---------------------------------------------------------------------------
// Transpose + fp32->bf16 convert: in[R][C] fp32 -> out[C][R] bf16.
// ---------------------------------------------------------------------------
__global__ __launch_bounds__(256) void transpose_f32_bf16(
    const float* __restrict__ in, u16* __restrict__ out, int R, int C)
{
    __shared__ float t[32][33];
    int bx = blockIdx.x * 32, by = blockIdx.y * 32;
    int x = threadIdx.x, y = threadIdx.y;
    #pragma unroll
    for (int j = 0; j < 32; j += 8)
        t[y + j][x] = in[(size_t)(by + y + j) * C + bx + x];
    __syncthreads();
    #pragma unroll
    for (int j = 0; j < 32; j += 8)
        out[(size_t)(bx + y + j) * R + by + x] = f2b(t[x][y + j]);
}

__global__ __launch_bounds__(256) void cvt_f32_bf16(
    const float* __restrict__ in, u16* __restrict__ out)
{
    size_t i = ((size_t)blockIdx.x * 256 + threadIdx.x) * 8;
    *(bf16x8*)(out + i) = ld8_cvt(in + i);
}

// ---------------------------------------------------------------------------
// 256x256 GEMM (8 waves), BK=32, counted-vmcnt dbuf + T2 source-swizzle.
// LDS swizzle (rule #21): LDS linear; global SOURCE chunk = chunk^((row>>1)&3)
// (so LDS[row][c] holds global[row][c^((row>>1)&3)]); ds_read chunk =
// quad^((lrow>>1)&3) (per-lane constant). 16-lane fragment reads then hit
// 8 distinct 4-bank groups 2-way each (free) instead of 8-way (R5: 3.1M
// SQ_LDS_BANK_CONFLICT).
// Epilogue: LDS-bounce -> full-line dwordx4 stores (R5: WRITE_SIZE 77.6MB
// for 33.5MB output = half-line RMW amplification from scalar u16 stores).
// ---------------------------------------------------------------------------
template<int EPI>
__global__ __launch_bounds__(512, 2) void gemm256(
    const u16* __restrict__ A, const u16* __restrict__ Bt, int N, int K,
    u16* __restrict__ C, const float* __restrict__ bias,
    u16* __restrict__ qo, u16* __restrict__ ko, u16* __restrict__ vo,
    const float* __restrict__ bq, const float* __restrict__ bk,
    const float* __restrict__ bv)
{
    __shared__ __align__(16) u16 Asm[2][256 * 32];
    __shared__ __align__(16) u16 Bsm[2][256 * 32];
    const int tid  = threadIdx.x;
    const int lane = tid & 63, wave = tid >> 6;
    const int lrow = lane & 15, quad = lane >> 4;
    const int wm = wave >> 2, wn = wave & 3;
    const int bm = blockIdx.x * 256, bn = blockIdx.y * 256;

    // staging: row = tid>>2 (and +128); source chunk xor-swizzled
    const int srow = tid >> 2;
    const int skolS = (((tid & 3) ^ ((tid >> 3) & 3)) * 8);   // source swizzle
    const u16* gA = A  + (size_t)(bm + srow) * K + skolS;
    const u16* gB = Bt + (size_t)(bn + srow) * K + skolS;
    const size_t rstep = (size_t)128 * K;   // (+128 rows: xor value unchanged)

    const int xq = quad ^ ((lrow >> 1) & 3);   // read-side chunk (per-lane const)

    f32x4 acc[8][4] = {};

#define STAGE256(T, BUF) do {                                              \
        glds16(gA + (size_t)(T) * 32,         &Asm[BUF][(size_t)tid * 8]); \
        glds16(gA + (size_t)(T) * 32 + rstep, &Asm[BUF][((size_t)tid + 512) * 8]); \
        glds16(gB + (size_t)(T) * 32,         &Bsm[BUF][(size_t)tid * 8]); \
        glds16(gB + (size_t)(T) * 32 + rstep, &Bsm[BUF][((size_t)tid + 512) * 8]); \
    } while (0)

    const int ntile = K >> 5;
    STAGE256(0, 0);
    STAGE256(1, 1);
    asm volatile("s_waitcnt vmcnt(4)" ::: "memory");
    __builtin_amdgcn_s_barrier();
    __builtin_amdgcn_sched_barrier(0);

    for (int t = 0; t < ntile; ++t) {
        const int cur = t & 1;
        bf16x8 af[8], bfr[4];
        #pragma unroll
        for (int mt = 0; mt < 8; mt++)
            af[mt] = *(const bf16x8*)&Asm[cur][(wm * 128 + mt * 16 + lrow) * 32 + xq * 8];
        #pragma unroll
        for (int nt = 0; nt < 4; nt++)
            bfr[nt] = *(const bf16x8*)&Bsm[cur][(wn * 64 + nt * 16 + lrow) * 32 + xq * 8];
        #pragma unroll
        for (int mt = 0; mt < 8; mt++)
            #pragma unroll
            for (int nt = 0; nt < 4; nt++)
                acc[mt][nt] = __builtin_amdgcn_mfma_f32_16x16x32_bf16(
                    af[mt], bfr[nt], acc[mt][nt], 0, 0, 0);

        if (t + 1 < ntile) {
            __builtin_amdgcn_sched_barrier(0);
            __builtin_amdgcn_s_barrier();
            if (t + 2 < ntile) {
                STAGE256(t + 2, cur);
                asm volatile("s_waitcnt vmcnt(4)" ::: "memory");
            } else {
                asm volatile("s_waitcnt vmcnt(0)" ::: "memory");
            }
            __builtin_amdgcn_s_barrier();
            __builtin_amdgcn_sched_barrier(0);
        }
    }
#undef STAGE256

    // ---- coalesced epilogue via per-wave LDS bounce ----
    __syncthreads();   // all waves done reading Asm/Bsm
    constexpr int STR = (EPI == 2) ? 64 : 68;   // pad rows for EPI0/1 readback
    u16* stg = ((u16*)Asm) + wave * 1152;       // 16*STR <= 1152, 8 waves fit

    const int colb = bn + wn * 64;
    float bval[4];
    u16* dstp = nullptr;
    int hh = 0, bb = 0;
    if (EPI == 2) {
        int mat = colb >> 10, dcol0 = colb & 1023;
        hh = dcol0 >> 6;
        const float* bp = (mat == 0) ? bq : ((mat == 1) ? bk : bv);
        #pragma unroll
        for (int nt = 0; nt < 4; nt++) bval[nt] = bp[dcol0 + nt * 16 + lrow];
        dstp = (mat == 0) ? qo : ((mat == 1) ? ko : vo);
        bb = (bm + wm * 128) >> 9;   // constant per block (bm 256-aligned)
    } else {
        #pragma unroll
        for (int nt = 0; nt < 4; nt++) bval[nt] = bias[colb + nt * 16 + lrow];
    }

    #pragma unroll
    for (int mt = 0; mt < 8; mt++) {
        const int row0 = bm + wm * 128 + mt * 16;
        #pragma unroll
        for (int nt = 0; nt < 4; nt++)
            #pragma unroll
            for (int r = 0; r < 4; r++) {
                float v = acc[mt][nt][r] + bval[nt];
                if (EPI == 1) v = 0.5f * v * (1.0f + erff(v * 0.70710678118654752f));
                stg[(quad * 4 + r) * STR + nt * 16 + lrow] = f2b(v);
            }
        // wave-private region; per-wave LDS ops are in-order, compiler
        // inserts lgkmcnt before the dependent readback.
        if (EPI == 2) {
            int s0 = row0 & 511;
            size_t base = (((size_t)(bb * 16 + hh)) * 512 + s0) * 64;
            #pragma unroll
            for (int i = 0; i < 2; i++)
                *(bf16x8*)(dstp + base + (size_t)(i * 64 + lane) * 8) =
                    *(const bf16x8*)&stg[(i * 64 + lane) * 8];
        } else {
            #pragma unroll
            for (int i = 0; i < 2; i++) {
                int rl = i * 8 + (lane >> 3);
                *(bf16x8*)(C + (size_t)(row0 + rl) * N + colb + (lane & 7) * 8) =
                    *(const bf16x8*)&stg[rl * STR + (lane & 7) * 8];
            }
        }
    }
}

// ---------------------------------------------------------------------------
// 128xBN GEMM (4 waves) — counted-vmcnt dbuf + T2 source-swizzle.
// Used for N=1024 GEMMs (Wo, W2). Epilogue unchanged (isolation).
// ---------------------------------------------------------------------------
template<int EPI, int BN>
__global__ __launch_bounds__(256) void gemm_bt(
    const u16* __restrict__ A, const u16* __restrict__ Bt, int N, int K,
    u16* __restrict__ C, const float* __restrict__ bias,
    u16* __restrict__ qo, u16* __restrict__ ko, u16* __restrict__ vo,
    const float* __restrict__ bq, const float* __restrict__ bk,
    const float* __restrict__ bv)
{
    __shared__ __align__(16) u16 Asm[2][128 * 32];
    __shared__ __align__(16) u16 Bsm[2][BN * 32];
    const int tid  = threadIdx.x;
    const int lane = tid & 63;
    const int wave = tid >> 6;
    const int lrow = lane & 15, quad = lane >> 4;
    const int bm = blockIdx.x * 128, bn = blockIdx.y * BN;

    const int srow = tid >> 2;
    const int skolS = (((tid & 3) ^ ((tid >> 3) & 3)) * 8);   // source swizzle
    const u16* gA0 = A  + (size_t)(bm + srow) * K + skolS;
    const u16* gA1 = gA0 + (size_t)64 * K;     // +64 rows: xor unchanged
    const u16* gB0 = Bt + (size_t)(bn + srow) * K + skolS;
    const u16* gB1 = gB0 + (size_t)64 * K;

    const int xq = quad ^ ((lrow >> 1) & 3);

    const int wm = wave >> 1, wn = wave & 1;
    constexpr int NT = (BN == 128) ? 4 : 2;
    f32x4 acc[4][NT] = {};

    glds16(gA0, &Asm[0][(size_t)tid * 8]);
    glds16(gA1, &Asm[0][((size_t)tid + 256) * 8]);
    if constexpr (BN == 128) glds16(gB1, &Bsm[0][((size_t)tid + 256) * 8]);
    glds16(gB0, &Bsm[0][(size_t)tid * 8]);

    int cur = 0;
    for (int kt = 0; kt < K; kt += 32) {
        const int nxt = kt + 32;
        if (nxt < K) {
            glds16(gA0 + nxt, &Asm[cur ^ 1][(size_t)tid * 8]);
            glds16(gA1 + nxt, &Asm[cur ^ 1][((size_t)tid + 256) * 8]);
            if constexpr (BN == 128)
                glds16(gB1 + nxt, &Bsm[cur ^ 1][((size_t)tid + 256) * 8]);
            glds16(gB0 + nxt, &Bsm[cur ^ 1][(size_t)tid * 8]);
            if constexpr (BN == 128)
                asm volatile("s_waitcnt vmcnt(4)" ::: "memory");
            else
                asm volatile("s_waitcnt vmcnt(3)" ::: "memory");
        } else {
            asm volatile("s_waitcnt vmcnt(0)" ::: "memory");
        }
        __builtin_amdgcn_s_barrier();
        __builtin_amdgcn_sched_barrier(0);

        bf16x8 af[4], bfr[NT];
        #pragma unroll
        for (int mt = 0; mt < 4; mt++)
            af[mt] = *(const bf16x8*)&Asm[cur][(wm * 64 + mt * 16 + lrow) * 32 + xq * 8];
        #pragma unroll
        for (int nt = 0; nt < NT; nt++)
            bfr[nt] = *(const bf16x8*)&Bsm[cur][(wn * (BN / 2) + nt * 16 + lrow) * 32 + xq * 8];
        #pragma unroll
        for (int mt = 0; mt < 4; mt++)
            #pragma unroll
            for (int nt = 0; nt < NT; nt++)
                acc[mt][nt] = __builtin_amdgcn_mfma_f32_16x16x32_bf16(
                    af[mt], bfr[nt], acc[mt][nt], 0, 0, 0);

        __builtin_amdgcn_sched_barrier(0);
        __builtin_amdgcn_s_barrier();
        cur ^= 1;
    }

    #pragma unroll
    for (int nt = 0; nt < NT; nt++) {
        int col = bn + wn * (BN / 2) + nt * 16 + lrow;
        int mat = 0, hh = 0, dd = 0;
        float bval;
        if (EPI == 2) {
            mat  = col >> 10; int dcol = col & 1023;
            hh = dcol >> 6;   dd = dcol & 63;
            const float* bp = (mat == 0) ? bq : ((mat == 1) ? bk : bv);
            bval = bp[dcol];
        } else {
            bval = bias[col];
        }
        #pragma unroll
        for (int mt = 0; mt < 4; mt++) {
            #pragma unroll
            for (int r = 0; r < 4; r++) {
                int row = bm + wm * 64 + mt * 16 + quad * 4 + r;
                float v = acc[mt][nt][r] + bval;
                if (EPI == 1) v = 0.5f * v * (1.0f + erff(v * 0.70710678118654752f));
                if (EPI == 2) {
                    int b = row >> 9, s = row & 511;
                    u16* dst = (mat == 0) ? qo : ((mat == 1) ? ko : vo);
                    dst[(((size_t)(b * 16 + hh)) * 512 + s) * 64 + dd] = f2b(v);
                } else {
                    C[(size_t)row * N + col] = f2b(v);
                }
            }
        }
    }
}

// ---------------------------------------------------------------------------
// Flash attention: 2-phase pipeline (R3-verified) + K-tile source-swizzle.
// Ksm rows are 128 B -> unswizzled K-fragment reads were a 16-WAY bank
// conflict (all 16 lrow-lanes in one 4-bank group). Source chunk ^= row&7,
// read chunk = quad^(lrow&7) / (quad+4)^(lrow&7): 2-way max. V/Psm unchanged.
// ---------------------------------------------------------------------------
__global__ __launch_bounds__(256) void attn_kernel(
    const u16* __restrict__ Q, const u16* __restrict__ Kb, const u16* __restrict__ Vb,
    const float* __restrict__ adj, const int* __restrict__ mask, u16* __restrict__ ctx)
{
    const int S = 512, H = 16;
    __shared__ __align__(16) u16 Ksm[2][32 * 64];
    __shared__ __align__(16) u16 Vt [2][64 * 32];
    __shared__ __align__(16) u16 Psm[4][16 * 32];

    int tid = threadIdx.x, lane = tid & 63, wave = tid >> 6;
    int lrow = lane & 15, quad = lane >> 4;

    int orig = (blockIdx.z * 16 + blockIdx.y) * 8 + blockIdx.x;
    int b  = orig & 7;
    int h  = (orig >> 3) & 15;
    int qt = orig >> 7;

    size_t headoff = ((size_t)(b * H + h)) * S * 64;
    const u16* qp = Q + headoff;
    const u16* kp = Kb + headoff;
    const u16* vp = Vb + headoff;
    const float* adjb = adj + (size_t)b * S * S;
    const int* maskb = mask + b * S;
    int q0 = qt * 64 + wave * 16;

    bf16x8 qf0 = *(const bf16x8*)(qp + (size_t)(q0 + lrow) * 64 + quad * 8);
    bf16x8 qf1 = *(const bf16x8*)(qp + (size_t)(q0 + lrow) * 64 + 32 + quad * 8);

    float m_run[4] = {-1e30f, -1e30f, -1e30f, -1e30f};
    float l_run[4] = {0.f, 0.f, 0.f, 0.f};
    f32x4 o[4] = {};

    int str = tid >> 3;                                // staging row (key)
    int stc = (tid & 7) * 8;                           // LDS dest col (linear)
    int stcS = (((tid & 7) ^ ((tid >> 3) & 7)) * 8);   // swizzled source col
    const int xk = lrow & 7;                           // read-side xor

    glds16(kp + (size_t)str * 64 + stcS, &Ksm[0][str * 64 + stc]);
    bf16x8 vcur = *(const bf16x8*)(vp + (size_t)str * 64 + stc);
    __syncthreads();

    int cur = 0;
    for (int kt = 0; kt < S; kt += 32) {
        const int nxt = kt + 32;
        bf16x8 vnxt;
        if (nxt < S) {
            glds16(kp + (size_t)(nxt + str) * 64 + stcS, &Ksm[cur ^ 1][str * 64 + stc]);
            vnxt = *(const bf16x8*)(vp + (size_t)(nxt + str) * 64 + stc);
        }
        {
            const u16* tv = (const u16*)&vcur;
            #pragma unroll
            for (int j = 0; j < 8; j++) Vt[cur][(stc + j) * 32 + str] = tv[j];
        }
        float adjv[2][4];
        #pragma unroll
        for (int f = 0; f < 2; f++)
            #pragma unroll
            for (int r = 0; r < 4; r++)
                adjv[f][r] = adjb[(size_t)(q0 + quad * 4 + r) * S + kt + f * 16 + lrow];

        f32x4 sc[2];
        #pragma unroll
        for (int f = 0; f < 2; f++) {
            f32x4 cf = {};
            bf16x8 kf0 = *(const bf16x8*)&Ksm[cur][(f * 16 + lrow) * 64 + (quad ^ xk) * 8];
            bf16x8 kf1 = *(const bf16x8*)&Ksm[cur][(f * 16 + lrow) * 64 + ((quad + 4) ^ xk) * 8];
            cf = __builtin_amdgcn_mfma_f32_16x16x32_bf16(qf0, kf0, cf, 0, 0, 0);
            cf = __builtin_amdgcn_mfma_f32_16x16x32_bf16(qf1, kf1, cf, 0, 0, 0);
            int key = kt + f * 16 + lrow;
            float mterm = maskb[key] ? -1e9f : 0.0f;
            #pragma unroll
            for (int r = 0; r < 4; r++)
                sc[f][r] = cf[r] * 0.125f + mterm + adjv[f][r];
        }

        float mx[4], al[4], sm[4];
        #pragma unroll
        for (int r = 0; r < 4; r++) mx[r] = fmaxf(sc[0][r], sc[1][r]);
        #pragma unroll
        for (int mk = 1; mk < 16; mk <<= 1)
            #pragma unroll
            for (int r = 0; r < 4; r++) mx[r] = fmaxf(mx[r], __shfl_xor(mx[r], mk));
        #pragma unroll
        for (int r = 0; r < 4; r++) {
            float mn = fmaxf(m_run[r], mx[r]);
            al[r] = __expf(fminf(m_run[r] - mn, 0.f));
            m_run[r] = mn;
        }
        #pragma unroll
        for (int f = 0; f < 2; f++)
            #pragma unroll
            for (int r = 0; r < 4; r++)
                sc[f][r] = __expf(fminf(sc[f][r] - m_run[r], 0.f));
        #pragma unroll
        for (int r = 0; r < 4; r++) sm[r] = sc[0][r] + sc[1][r];
        #pragma unroll
        for (int mk = 1; mk < 16; mk <<= 1)
            #pragma unroll
            for (int r = 0; r < 4; r++) sm[r] += __shfl_xor(sm[r], mk);
        #pragma unroll
        for (int r = 0; r < 4; r++) l_run[r] = l_run[r] * al[r] + sm[r];
        #pragma unroll
        for (int nt = 0; nt < 4; nt++)
            #pragma unroll
            for (int r = 0; r < 4; r++) o[nt][r] *= al[r];

        #pragma unroll
        for (int f = 0; f < 2; f++)
            #pragma unroll
            for (int r = 0; r < 4; r++)
                Psm[wave][(quad * 4 + r) * 32 + f * 16 + lrow] = f2b(sc[f][r]);
        bf16x8 pa = *(const bf16x8*)&Psm[wave][lrow * 32 + quad * 8];

        __syncthreads();
        #pragma unroll
        for (int nt = 0; nt < 4; nt++) {
            bf16x8 vf = *(const bf16x8*)&Vt[cur][(nt * 16 + lrow) * 32 + quad * 8];
            o[nt] = __builtin_amdgcn_mfma_f32_16x16x32_bf16(pa, vf, o[nt], 0, 0, 0);
        }
        if (nxt < S) vcur = vnxt;
        cur ^= 1;
    }

    #pragma unroll
    for (int nt = 0; nt < 4; nt++)
        #pragma unroll
        for (int r = 0; r < 4; r++) {
            int qrow = q0 + quad * 4 + r;
            ctx[((size_t)b * 512 + qrow) * 1024 + h * 64 + nt * 16 + lrow] =
                f2b(o[nt][r] / l_run[r]);
        }
}

// ---------------------------------------------------------------------------
// out = LayerNorm(X + Y) (unchanged)
// ---------------------------------------------------------------------------
template<int MODE>
__global__ __launch_bounds__(256) void add_ln(
    const void* __restrict__ Xv, const void* __restrict__ Yv,
    const float* __restrict__ gamma, const float* __restrict__ beta,
    void* __restrict__ outv)
{
    const int D = 1024;
    int row = blockIdx.x, tid = threadIdx.x;
    int lane = tid & 63, wave = tid >> 6;
    size_t base = (size_t)row * D + tid * 4;

    float x[4];
    if (MODE == 0) {
        float4 xf = *(const float4*)((const float*)Xv + base);
        u16x4  uy = *(const u16x4*)((const u16*)Yv + base);
        x[0] = xf.x + b2f(uy[0]); x[1] = xf.y + b2f(uy[1]);
        x[2] = xf.z + b2f(uy[2]); x[3] = xf.w + b2f(uy[3]);
    } else {
        u16x4 ux = *(const u16x4*)((const u16*)Xv + base);
        u16x4 uy = *(const u16x4*)((const u16*)Yv + base);
        #pragma unroll
        for (int j = 0; j < 4; j++) x[j] = b2f(ux[j]) + b2f(uy[j]);
    }

    float s = x[0] + x[1] + x[2] + x[3];
    #pragma unroll
    for (int mk = 1; mk < 64; mk <<= 1) s += __shfl_xor(s, mk);
    __shared__ float red[8];
    if (lane == 0) red[wave] = s;
    __syncthreads();
    float mean = (red[0] + red[1] + red[2] + red[3]) * (1.0f / 1024.0f);

    float c[4], q = 0.f;
    #pragma unroll
    for (int j = 0; j < 4; j++) { c[j] = x[j] - mean; q += c[j] * c[j]; }
    #pragma unroll
    for (int mk = 1; mk < 64; mk <<= 1) q += __shfl_xor(q, mk);
    if (lane == 0) red[4 + wave] = q;
    __syncthreads();
    float var = (red[4] + red[5] + red[6] + red[7]) * (1.0f / 1023.0f);
    float inv = 1.0f / (sqrtf(var) + 1e-6f);

    float4 g4 = *(const float4*)(gamma + tid * 4);
    float4 b4 = *(const float4*)(beta + tid * 4);
    float gv[4] = {g4.x, g4.y, g4.z, g4.w};
    float bv[4] = {b4.x, b4.y, b4.z, b4.w};
    if (MODE == 0) {
        u16x4 ov;
        #pragma unroll
        for (int j = 0; j < 4; j++) ov[j] = f2b(gv[j] * c[j] * inv + bv[j]);
        *(u16x4*)((u16*)outv + base) = ov;
    } else {
        float4 ov;
        ov.x = gv[0] * c[0] * inv + bv[0];
        ov.y = gv[1] * c[1] * inv + bv[1];
        ov.z = gv[2] * c[2] * inv + bv[2];
        ov.w = gv[3] * c[3] * inv + bv[3];
        *(float4*)((float*)outv + base) = ov;
    }
}

// ---------------------------------------------------------------------------
// Workspace layout unchanged.
// ---------------------------------------------------------------------------
extern "C" void kernel_launch(void* const* d_in, const int* in_sizes, int n_in,
                              void* d_out, int out_size, void* d_ws, size_t ws_size,
                              hipStream_t stream)
{
    const float* x    = (const float*)d_in[0];
    const int*   mask = (const int*)d_in[1];
    const float* adj  = (const float*)d_in[2];
    const float* Wq = (const float*)d_in[4];  const float* bq = (const float*)d_in[5];
    const float* Wk = (const float*)d_in[6];  const float* bk = (const float*)d_in[7];
    const float* Wv = (const float*)d_in[8];  const float* bv = (const float*)d_in[9];
    const float* Wo = (const float*)d_in[10]; const float* bo = (const float*)d_in[11];
    const float* W1 = (const float*)d_in[12]; const float* b1 = (const float*)d_in[13];
    const float* W2 = (const float*)d_in[14]; const float* b2 = (const float*)d_in[15];
    const float* gamma = (const float*)d_in[16];
    const float* beta  = (const float*)d_in[17];
    float* out = (float*)d_out;

    const size_t MB = 1024ull * 1024;
    char* w = (char*)d_ws;
    u16* Wqkv_t = (u16*)(w + 0 * MB);
    u16* Wo_t   = (u16*)(w + 6 * MB);
    u16* W1_t   = (u16*)(w + 8 * MB);
    u16* W2_t   = (u16*)(w + 16 * MB);
    u16* out1   = (u16*)(w + 24 * MB);
    u16* qg     = (u16*)(w + 56 * MB);
    u16* kg     = (u16*)(w + 64 * MB);
    u16* vg     = (u16*)(w + 72 * MB);
    u16* ctxg   = (u16*)(w + 80 * MB);
    u16* aog    = (u16*)(w + 88 * MB);
    u16* hid    = (u16*)(w + 56 * MB);
    u16* ffn    = (u16*)(w + 88 * MB);

    dim3 tb(32, 8);
    transpose_f32_bf16<<<dim3(32, 32),  tb, 0, stream>>>(Wq, Wqkv_t,                1024, 1024);
    transpose_f32_bf16<<<dim3(32, 32),  tb, 0, stream>>>(Wk, Wqkv_t + 1024ull*1024, 1024, 1024);
    transpose_f32_bf16<<<dim3(32, 32),  tb, 0, stream>>>(Wv, Wqkv_t + 2048ull*1024, 1024, 1024);
    transpose_f32_bf16<<<dim3(32, 32),  tb, 0, stream>>>(Wo, Wo_t,                  1024, 1024);
    transpose_f32_bf16<<<dim3(128, 32), tb, 0, stream>>>(W1, W1_t,                  1024, 4096);
    transpose_f32_bf16<<<dim3(32, 128), tb, 0, stream>>>(W2, W2_t,                  4096, 1024);

    // ---- attention phase ----
    for (int g = 0; g < 4; g++) {
        const float* xg = x + (size_t)g * 4096 * 1024;
        cvt_f32_bf16<<<2048, 256, 0, stream>>>(xg, aog);
        gemm256<2><<<dim3(16, 12), 512, 0, stream>>>(aog, Wqkv_t, 3072, 1024,
            nullptr, nullptr, qg, kg, vg, bq, bk, bv);
        attn_kernel<<<dim3(8, 16, 8), 256, 0, stream>>>(qg, kg, vg,
            adj + (size_t)g * 8 * 512 * 512, mask + g * 8 * 512, ctxg);
        gemm_bt<0, 64><<<dim3(32, 16), 256, 0, stream>>>(ctxg, Wo_t, 1024, 1024,
            aog, bo, nullptr, nullptr, nullptr, nullptr, nullptr, nullptr);
        add_ln<0><<<4096, 256, 0, stream>>>(xg, aog, gamma, beta,
            out1 + (size_t)g * 4096 * 1024);
    }

    // ---- FFN phase ----
    for (int c = 0; c < 4; c++) {
        const u16* o1c = out1 + (size_t)c * 4096 * 1024;
        gemm256<1><<<dim3(16, 16), 512, 0, stream>>>(o1c, W1_t, 4096, 1024,
            hid, b1, nullptr, nullptr, nullptr, nullptr, nullptr, nullptr);
        gemm_bt<0, 64><<<dim3(32, 16), 256, 0, stream>>>(hid, W2_t, 1024, 4096,
            ffn, b2, nullptr, nullptr, nullptr, nullptr, nullptr, nullptr);
        add_ln<1><<<4096, 256, 0, stream>>>(o1c, ffn, gamma, beta,
            out + (size_t)c * 4096 * 1024);
    }
}